// Round 1
// baseline (3797.205 us; speedup 1.0000x reference)
//
#include <hip/hip_runtime.h>

#define NB 512     // batch
#define NH 512     // hidden
#define NG 2048    // 4*H
#define NF 32      // input features
#define NS 64      // output steps / seq len
#define NO 32      // output dim

// ---------------- utility: zero init (h0, h1, c) ----------------
__global__ __launch_bounds__(256)
void zero_ws_k(float* __restrict__ p, int n) {
    int i = blockIdx.x * 256 + threadIdx.x;
    int stride = gridDim.x * 256;
    for (; i < n; i += stride) p[i] = 0.f;
}

// ---------------- prep: Wh' = Wh + Wd@Wx ----------------
__global__ __launch_bounds__(256)
void prep_whp_k(const float* __restrict__ Wh, const float* __restrict__ Wd,
                const float* __restrict__ Wx, float* __restrict__ Whp) {
    __shared__ float wd[32];
    const int k = blockIdx.x;
    const int tid = threadIdx.x;
    if (tid < 32) wd[tid] = Wd[k * NO + tid];
    __syncthreads();
    for (int c = tid; c < NG; c += 256) {
        float s = Wh[(size_t)k * NG + c];
        #pragma unroll
        for (int o = 0; o < 32; ++o) s += wd[o] * Wx[(size_t)o * NG + c];
        Whp[(size_t)k * NG + c] = s;
    }
}

// ---------------- prep: b' = b + bd@Wx ----------------
__global__ __launch_bounds__(256)
void prep_bp_k(const float* __restrict__ b, const float* __restrict__ bd,
               const float* __restrict__ Wx, float* __restrict__ bp) {
    const int c = blockIdx.x * 256 + threadIdx.x;
    float s = b[c];
    #pragma unroll
    for (int o = 0; o < 32; ++o) s += bd[o] * Wx[(size_t)o * NG + c];
    bp[c] = s;
}

// ---------------- fused LSTM step ----------------
// Tile: 32 rows (batch) x 16 j (hidden cols) -> 128 output cols across 4 gates.
// Grid: (512/32) * (512/16) = 16 * 32 = 512 blocks, 256 threads.
// Thread (tx=j local 0..15, ty=0..15): rows ty*2+{0,1}, 4 gates of one j each
// -> completes the cell update (c,h) locally, no extra sync.
// EMIT_PRED: epilogue computes pred_{s-1}[rows][o=jt] = h_in@Wd + bd (K split 8 ways).
template<bool HAS_X, bool EMIT_PRED>
__global__ __launch_bounds__(256, 2)
void lstm_step_k(const float* __restrict__ h_in,
                 float* __restrict__ c_st,
                 float* __restrict__ h_out,
                 const float* __restrict__ W,     // (512, 2048) Wh or Wh'
                 const float* __restrict__ bias,  // (2048,) b or b'
                 const float* __restrict__ x_t,   // (512, *) row stride NS*NF, or null
                 const float* __restrict__ Wx,    // (32, 2048) or null
                 const float* __restrict__ Wd,    // (512, 32) or null
                 const float* __restrict__ bd,    // (32,) or null
                 float* __restrict__ out,         // (B, S, O) or null
                 int s_out)
{
    __shared__ float As[32][68];   // [row][k]  (read: broadcast over tx)
    __shared__ float Bs[64][68];   // [k][gate*16+j]  (read: conflict-free)
    __shared__ float red[8][32];

    const int tid = threadIdx.x;
    const int tx = tid & 15;
    const int ty = tid >> 4;
    const int jt = blockIdx.x & 31;
    const int rt = blockIdx.x >> 5;
    const int rowBase = rt * 32;
    const int jBase = jt * 16;

    float acc00 = 0.f, acc01 = 0.f, acc02 = 0.f, acc03 = 0.f;
    float acc10 = 0.f, acc11 = 0.f, acc12 = 0.f, acc13 = 0.f;

    const int arow = tid >> 3;          // 0..31
    const int af0 = (tid & 7) * 8;      // 8 floats (2 float4) per thread
    const int bf4 = tid & 15;
    const int bkk0 = tid >> 4;
    const int bgate = bf4 >> 2;
    const int bj4 = (bf4 & 3) * 4;

    // ---- main K loop over recurrent weight: 8 chunks of 64 ----
    for (int k0 = 0; k0 < NH; k0 += 64) {
        {
            const float* ap = &h_in[(size_t)(rowBase + arow) * NH + k0 + af0];
            float4 av0 = *(const float4*)ap;
            float4 av1 = *(const float4*)(ap + 4);
            *(float4*)&As[arow][af0] = av0;
            *(float4*)&As[arow][af0 + 4] = av1;
        }
        #pragma unroll
        for (int p = 0; p < 4; ++p) {
            int kk = bkk0 + p * 16;
            float4 v = *(const float4*)&W[(size_t)(k0 + kk) * NG + bgate * NH + jBase + bj4];
            *(float4*)&Bs[kk][bf4 * 4] = v;
        }
        __syncthreads();
        #pragma unroll
        for (int kk = 0; kk < 64; ++kk) {
            float a0 = As[ty * 2][kk];
            float a1 = As[ty * 2 + 1][kk];
            float b0 = Bs[kk][tx];
            float b1 = Bs[kk][16 + tx];
            float b2 = Bs[kk][32 + tx];
            float b3 = Bs[kk][48 + tx];
            acc00 += a0 * b0; acc01 += a0 * b1; acc02 += a0 * b2; acc03 += a0 * b3;
            acc10 += a1 * b0; acc11 += a1 * b1; acc12 += a1 * b2; acc13 += a1 * b3;
        }
        __syncthreads();
    }

    // ---- x_t @ Wx contribution (warmup only), K = 32 ----
    if (HAS_X) {
        {
            int row = tid >> 3;
            int f = (tid & 7) * 4;
            float4 v = *(const float4*)&x_t[(size_t)(rowBase + row) * (NS * NF) + f];
            *(float4*)&As[row][f] = v;
        }
        #pragma unroll
        for (int p = 0; p < 2; ++p) {
            int kk = bkk0 + p * 16;
            float4 v = *(const float4*)&Wx[(size_t)kk * NG + bgate * NH + jBase + bj4];
            *(float4*)&Bs[kk][bf4 * 4] = v;
        }
        __syncthreads();
        #pragma unroll
        for (int kk = 0; kk < 32; ++kk) {
            float a0 = As[ty * 2][kk];
            float a1 = As[ty * 2 + 1][kk];
            float b0 = Bs[kk][tx];
            float b1 = Bs[kk][16 + tx];
            float b2 = Bs[kk][32 + tx];
            float b3 = Bs[kk][48 + tx];
            acc00 += a0 * b0; acc01 += a0 * b1; acc02 += a0 * b2; acc03 += a0 * b3;
            acc10 += a1 * b0; acc11 += a1 * b1; acc12 += a1 * b2; acc13 += a1 * b3;
        }
    }

    // ---- cell epilogue: gates i,f,g,o ; c,h update ----
    {
        const int j = jBase + tx;
        const float bi = bias[j];
        const float bf_ = bias[NH + j];
        const float bg = bias[2 * NH + j];
        const float bo = bias[3 * NH + j];
        #pragma unroll
        for (int r = 0; r < 2; ++r) {
            float zi = (r ? acc10 : acc00) + bi;
            float zf = (r ? acc11 : acc01) + bf_;
            float zg = (r ? acc12 : acc02) + bg;
            float zo = (r ? acc13 : acc03) + bo;
            float ig = 1.f / (1.f + __expf(-zi));
            float fg = 1.f / (1.f + __expf(-zf));
            float gg = 1.f - 2.f / (1.f + __expf(2.f * zg));   // tanh
            float og = 1.f / (1.f + __expf(-zo));
            int bidx = rowBase + ty * 2 + r;
            int idx = bidx * NH + j;
            float cn = fg * c_st[idx] + ig * gg;
            float hn = og * (1.f - 2.f / (1.f + __expf(2.f * cn)));
            c_st[idx] = cn;
            h_out[idx] = hn;
        }
    }

    // ---- pred epilogue: pred_{s_out}[rowBase..+31][o=jt] from h_in ----
    if (EMIT_PRED) {
        const int row = tid & 31;
        const int ks = tid >> 5;   // 8-way K split (64 each)
        const int o = jt;          // jt in 0..31 == output column
        const float* hrow = &h_in[(size_t)(rowBase + row) * NH + ks * 64];
        const float* wcol = &Wd[(size_t)(ks * 64) * NO + o];
        float pacc = 0.f;
        #pragma unroll
        for (int q = 0; q < 16; ++q) {
            float4 hv = *(const float4*)&hrow[q * 4];
            pacc += hv.x * wcol[(q * 4 + 0) * NO];
            pacc += hv.y * wcol[(q * 4 + 1) * NO];
            pacc += hv.z * wcol[(q * 4 + 2) * NO];
            pacc += hv.w * wcol[(q * 4 + 3) * NO];
        }
        red[ks][row] = pacc;
        __syncthreads();
        if (tid < 32) {
            float s = red[0][tid] + red[1][tid] + red[2][tid] + red[3][tid]
                    + red[4][tid] + red[5][tid] + red[6][tid] + red[7][tid];
            out[((size_t)(rowBase + tid) * NS + s_out) * NO + o] = s + bd[o];
        }
    }
}

// ---------------- final prediction: pred_63 = h_63 @ Wd + bd ----------------
__global__ __launch_bounds__(256)
void final_pred_k(const float* __restrict__ h_in, const float* __restrict__ Wd,
                  const float* __restrict__ bd, float* __restrict__ out)
{
    __shared__ float hs[32][68];
    const int tid = threadIdx.x;
    const int tx = tid & 31;       // o
    const int ty = tid >> 5;       // row group
    const int rowBase = blockIdx.x * 32;
    float a0 = 0.f, a1 = 0.f, a2 = 0.f, a3 = 0.f;
    for (int k0 = 0; k0 < NH; k0 += 64) {
        int row = tid >> 3;
        int f0 = (tid & 7) * 8;
        const float* hp = &h_in[(size_t)(rowBase + row) * NH + k0 + f0];
        float4 v0 = *(const float4*)hp;
        float4 v1 = *(const float4*)(hp + 4);
        *(float4*)&hs[row][f0] = v0;
        *(float4*)&hs[row][f0 + 4] = v1;
        __syncthreads();
        #pragma unroll
        for (int kk = 0; kk < 64; ++kk) {
            float w = Wd[(size_t)(k0 + kk) * NO + tx];
            a0 += hs[ty * 4 + 0][kk] * w;
            a1 += hs[ty * 4 + 1][kk] * w;
            a2 += hs[ty * 4 + 2][kk] * w;
            a3 += hs[ty * 4 + 3][kk] * w;
        }
        __syncthreads();
    }
    float bv = bd[tx];
    out[((size_t)(rowBase + ty * 4 + 0) * NS + 63) * NO + tx] = a0 + bv;
    out[((size_t)(rowBase + ty * 4 + 1) * NS + 63) * NO + tx] = a1 + bv;
    out[((size_t)(rowBase + ty * 4 + 2) * NS + 63) * NO + tx] = a2 + bv;
    out[((size_t)(rowBase + ty * 4 + 3) * NS + 63) * NO + tx] = a3 + bv;
}

extern "C" void kernel_launch(void* const* d_in, const int* in_sizes, int n_in,
                              void* d_out, int out_size, void* d_ws, size_t ws_size,
                              hipStream_t stream) {
    (void)in_sizes; (void)n_in; (void)out_size; (void)ws_size;
    const float* x  = (const float*)d_in[0];   // (512, 64, 32)
    const float* Wx = (const float*)d_in[1];   // (32, 2048)
    const float* Wh = (const float*)d_in[2];   // (512, 2048)
    const float* b  = (const float*)d_in[3];   // (2048,)
    const float* Wd = (const float*)d_in[4];   // (512, 32)
    const float* bd = (const float*)d_in[5];   // (32,)
    float* out = (float*)d_out;                // (512, 64, 32)

    float* w = (float*)d_ws;
    float* hb[2];
    hb[0]      = w;                    // 512*512
    hb[1]      = w + 262144;           // 512*512
    float* c   = w + 524288;           // 512*512
    float* Whp = w + 786432;           // 512*2048
    float* bp  = w + 1835008;          // 2048
    // total ws use: 1,837,056 floats = 7.35 MB

    // zero h0, h1, c (harness does not re-poison between replays)
    zero_ws_k<<<512, 256, 0, stream>>>(w, 786432);
    prep_whp_k<<<512, 256, 0, stream>>>(Wh, Wd, Wx, Whp);
    prep_bp_k<<<8, 256, 0, stream>>>(b, bd, Wx, bp);

    int p = 0;
    // warmup: 64 steps with x_t @ Wx
    for (int t = 0; t < 64; ++t) {
        lstm_step_k<true, false><<<512, 256, 0, stream>>>(
            hb[p], c, hb[p ^ 1], Wh, b, x + (size_t)t * NF, Wx,
            nullptr, nullptr, nullptr, 0);
        p ^= 1;
    }
    // decode: 63 steps with folded weights; step s emits pred_{s-1}
    for (int s = 1; s < 64; ++s) {
        lstm_step_k<false, true><<<512, 256, 0, stream>>>(
            hb[p], c, hb[p ^ 1], Whp, bp, nullptr, nullptr,
            Wd, bd, out, s - 1);
        p ^= 1;
    }
    // pred_63
    final_pred_k<<<16, 256, 0, stream>>>(hb[p], Wd, bd, out);
}